// Round 12
// baseline (336.159 us; speedup 1.0000x reference)
//
#include <hip/hip_runtime.h>
#include <hip/hip_bf16.h>
#include <math.h>

#define BATCH 8
#define SEQ   4096
#define DIM   64
#define LQ    2744            // int((1-0.33)*4096)
#define QPB   128             // queries per attn block
#define NQB   22              // ceil(2744/128)
#define QPAD  2816            // NQB*QPB
#define KS    4               // key splits (1024 keys per block) — R0 config
#define QSC   0.1803368801111204f   // 0.125 * log2(e), folded into Qh

typedef _Float16 half8 __attribute__((ext_vector_type(8)));
typedef short    bs8   __attribute__((ext_vector_type(8)));
typedef float    fx16  __attribute__((ext_vector_type(16)));
typedef unsigned short ushort_t;

union UH { uint4 u4; half8 h; };
union UB { unsigned u[4]; uint4 u4; bs8 s; };

__device__ __forceinline__ unsigned pack_bf16(float a, float b) {
    __hip_bfloat162 h = __float22bfloat162_rn(make_float2(a, b));
    union { __hip_bfloat162 h; unsigned u; } cv; cv.h = h; return cv.u;
}

// coherence-point read: device-scope atomic RMW (+0.0f), returns current.
__device__ __forceinline__ float aload(const float* p) {
    return atomicAdd((float*)p, 0.0f);
}

// ---------------- sortable-uint mapping ----------------
__device__ __forceinline__ unsigned f2sort(float f) {
    unsigned u = __float_as_uint(f);
    return (u & 0x80000000u) ? ~u : (u | 0x80000000u);
}
__device__ __forceinline__ float sort2f(unsigned u) {
    return __uint_as_float((u & 0x80000000u) ? (u & 0x7FFFFFFFu) : ~u);
}

struct RadSh {
    unsigned u[4096];
    unsigned hist[256];
    unsigned wsum[4];
    unsigned res[2];
    float    rsum[4];
    int      eq[256];
    int      cnts[2];
};

// ---------------- radix select, wave-level suffix scan (256 threads) -----
// pass_lo=0 exact 32-bit threshold; pass_lo=2 -> 16-bit prefix threshold
// (caller approximates the remainder bin).
__device__ void radix_select_4096(const unsigned* u, int k, unsigned* hist,
                                  unsigned* wsum, unsigned* res, int pass_lo) {
    const int t = threadIdx.x;
    const int lane = t & 63, wv = t >> 6;
    if (t == 0) { res[0] = 0u; res[1] = (unsigned)k; }
    for (int pass = 3; pass >= pass_lo; --pass) {
        const int shift = pass * 8;
        hist[t] = 0u;
        __syncthreads();
        const unsigned pref  = res[0];
        const unsigned kk    = res[1];
        const unsigned hmask = (pass == 3) ? 0u : (0xFFFFFFFFu << (shift + 8));
        for (int i = t; i < 4096; i += 256) {
            unsigned ui = u[i];
            if ((ui & hmask) == pref) atomicAdd(&hist[(ui >> shift) & 255u], 1u);
        }
        __syncthreads();
        const unsigned h = hist[t];
        unsigned s = h;
#pragma unroll
        for (int ofs = 1; ofs < 64; ofs <<= 1) {
            unsigned a = __shfl_down(s, ofs, 64);
            s += (lane + ofs < 64) ? a : 0u;
        }
        if (lane == 0) wsum[wv] = s;     // wave total (suffix at lane 0)
        __syncthreads();
#pragma unroll
        for (int w2 = 0; w2 < 4; ++w2)
            if (w2 > wv) s += wsum[w2];  // s = sum of hist[t..255]
        if (s >= kk && (s - h) < kk) {   // unique threshold bin
            res[0] = pref | ((unsigned)t << shift);
            res[1] = kk - (s - h);
        }
        __syncthreads();
    }
}

// ---------------- K1: projections (R9, proven) ---------------------------
// x rows are wave-uniform: readfirstlane-forced scalar loads.
__global__ __launch_bounds__(256) void proj_kernel(
    const float* __restrict__ x,  const float* __restrict__ Wq,
    const float* __restrict__ Wk, const float* __restrict__ Wv,
    float* __restrict__ Q, float* __restrict__ Kt,
    _Float16* __restrict__ Qh, _Float16* __restrict__ Kh,
    ushort_t* __restrict__ Vt, float* __restrict__ pmean) {
    const int rt = blockIdx.x, b = blockIdx.y, t = threadIdx.x;
    __shared__ float  red[4][64];
    const int ch = t & 63, rg = t >> 6;
    const float* xb = x + (size_t)b * SEQ * DIM;
    float accq[16], acck[16], accv[16];
#pragma unroll
    for (int i = 0; i < 16; ++i) { accq[i] = 0.f; acck[i] = 0.f; accv[i] = 0.f; }
    for (int dc = 0; dc < 4; ++dc) {
        float wq[16], wk[16], wv[16];
#pragma unroll
        for (int dd = 0; dd < 16; ++dd) {
            int d = dc * 16 + dd;
            wq[dd] = Wq[d * 64 + ch]; wk[dd] = Wk[d * 64 + ch]; wv[dd] = Wv[d * 64 + ch];
        }
        for (int r = 0; r < 16; ++r) {
            const int off = (rt * 64 + rg * 16 + r) * DIM + dc * 16;
            const float* xrow =
                xb + (unsigned)__builtin_amdgcn_readfirstlane(off);
            float xv[16];
#pragma unroll
            for (int dd = 0; dd < 16; ++dd) xv[dd] = xrow[dd];
#pragma unroll
            for (int dd = 0; dd < 16; ++dd) {
                accq[r] = fmaf(xv[dd], wq[dd], accq[r]);
                acck[r] = fmaf(xv[dd], wk[dd], acck[r]);
                accv[r] = fmaf(xv[dd], wv[dd], accv[r]);
            }
        }
    }
    const int rowbase = rt * 64 + rg * 16;
    float sv = 0.f;
#pragma unroll
    for (int r = 0; r < 16; ++r) {
        size_t o = ((size_t)b * SEQ + rowbase + r) * DIM + ch;
        Q[o]  = accq[r];
        Qh[o] = (_Float16)(accq[r] * QSC);
        Kh[o] = (_Float16)acck[r];
        sv += accv[r];
    }
    float4* ktp = (float4*)(Kt + ((size_t)b * 64 + ch) * SEQ + rowbase);
    ktp[0] = make_float4(acck[0], acck[1], acck[2], acck[3]);
    ktp[1] = make_float4(acck[4], acck[5], acck[6], acck[7]);
    ktp[2] = make_float4(acck[8], acck[9], acck[10], acck[11]);
    ktp[3] = make_float4(acck[12], acck[13], acck[14], acck[15]);
    // Vt bf16, k-permuted pair order per 16-group: [0,1,4,5,2,3,6,7]
    {
        unsigned pk[8];
#pragma unroll
        for (int i = 0; i < 8; ++i) pk[i] = pack_bf16(accv[2*i], accv[2*i+1]);
        uint4* vp = (uint4*)(Vt + ((size_t)(b * 64 + ch)) * SEQ + rowbase);
        vp[0] = make_uint4(pk[0], pk[1], pk[4], pk[5]);
        vp[1] = make_uint4(pk[2], pk[3], pk[6], pk[7]);
    }
    red[rg][ch] = sv;
    __syncthreads();
    if (rg == 0)
        pmean[((size_t)b * 64 + ch) * 64 + rt] =
            red[0][ch] + red[1][ch] + red[2][ch] + red[3][ch];
}

// ---------------- K2: kmean + full-region zeroing (R11 body, passed) -----
// 2-pass radix (16-bit threshold), remainder ~= bin midpoint. Each block
// zeroes its consumed 16KB Kt column (Kt aliases pout/pl + the completion
// counters at Kt+5,857,280): zeroing spread over 512 blocks, and the
// counters get auto-zeroed AFTER proj's Kt writes (R7's clobber lesson).
__global__ __launch_bounds__(256) void kmean_kernel(float* __restrict__ Kt,
                                                    const float* __restrict__ pmean,
                                                    float* __restrict__ Kred,
                                                    float* __restrict__ meanfin) {
    __shared__ RadSh sh;
    const int bc = blockIdx.x, t = threadIdx.x;
    if (t < 64) {
        float v = pmean[(size_t)bc * 64 + t];
        for (int m = 1; m < 64; m <<= 1) v += __shfl_xor(v, m, 64);
        if (t == 0) meanfin[bc] = v * (1.0f / (float)SEQ);
    }
    const float4* c4 = (const float4*)(Kt + (size_t)bc * SEQ);
    for (int i = t; i < 1024; i += 256) {
        float4 v = c4[i];
        sh.u[i*4+0] = f2sort(v.x); sh.u[i*4+1] = f2sort(v.y);
        sh.u[i*4+2] = f2sort(v.z); sh.u[i*4+3] = f2sort(v.w);
    }
    __syncthreads();
    {   // this block's Kt column consumed -> zero for pout/pl/cnt reuse
        float4* pz = (float4*)Kt + (size_t)bc * 1024;
        const float4 z = make_float4(0.f, 0.f, 0.f, 0.f);
        for (int i = t; i < 1024; i += 256) pz[i] = z;
    }
    radix_select_4096(sh.u, LQ, sh.hist, sh.wsum, sh.res, 2);
    const unsigned Tu = sh.res[0];          // bits 31..16 of threshold
    const int krem = (int)sh.res[1];
    float loc = 0.f;
    for (int i = t; i < 4096; i += 256)
        if ((sh.u[i] & 0xFFFF0000u) > Tu) loc += sort2f(sh.u[i]);
    for (int msk = 1; msk < 64; msk <<= 1) loc += __shfl_xor(loc, msk, 64);
    if ((t & 63) == 0) sh.rsum[t >> 6] = loc;
    __syncthreads();
    if (t == 0) {
        float s = sh.rsum[0] + sh.rsum[1] + sh.rsum[2] + sh.rsum[3]
                + (float)krem * sort2f(Tu | 0x8000u);   // bin midpoint
        Kred[bc] = s / (float)LQ;
    }
}

// ---------------- K3: sqk + mean-fill + last-finisher select -------------
// 128 blocks carry the 8.4MB Q read + 8.4MB mean-fill (R11 body, passed).
// sqk values go to global via atomicExch (coherence point). Each block:
// __syncthreads (compiler drains vmcnt before s_barrier -> exchanges
// complete) then t0 bumps cntS[b]. The 16th finisher per batch stages sqk
// via aload (coherence-point reads) and runs the R9 select verbatim.
// NO threadfence anywhere (R11 storm lesson).
struct Pre { float kr[64]; float4 mf4[16]; };
union SqSh { Pre p; RadSh r; };

__global__ __launch_bounds__(256) void sqk_select_kernel(
    const float* __restrict__ Q, const float* __restrict__ Kred,
    float* __restrict__ sqk, const float* __restrict__ meanf,
    int* __restrict__ cntS, int* __restrict__ sel, float* __restrict__ out) {
    const int b = blockIdx.y, t = threadIdx.x;
    const int l = blockIdx.x * 256 + t;
    __shared__ SqSh sh;
    __shared__ int amlast;
    if (t < 64) sh.p.kr[t] = Kred[b * 64 + t];
    if (t >= 64 && t < 80)
        sh.p.mf4[t - 64] = ((const float4*)(meanf + b * 64))[t - 64];
    __syncthreads();
    {
        const float4* q = (const float4*)(Q + ((size_t)b * SEQ + l) * DIM);
        float s = 0.f;
#pragma unroll
        for (int i = 0; i < 16; ++i) {
            float4 v = q[i];
            s = fmaf(v.x, sh.p.kr[i*4+0], s); s = fmaf(v.y, sh.p.kr[i*4+1], s);
            s = fmaf(v.z, sh.p.kr[i*4+2], s); s = fmaf(v.w, sh.p.kr[i*4+3], s);
        }
        atomicExch(&sqk[b * SEQ + l], s);     // data at coherence point
        float4* orow = (float4*)(out + ((size_t)b * SEQ + l) * DIM);
#pragma unroll
        for (int c = 0; c < 16; ++c) orow[c] = sh.p.mf4[c];
    }
    __syncthreads();        // drains all waves' vmem (exchanges complete)
    if (t == 0) amlast = (atomicAdd(&cntS[b], 1) == 15);
    __syncthreads();
    if (!amlast) return;

    // -------- select phase (16th finisher; R9 select body, no inv) ------
    const float* col = sqk + (size_t)b * SEQ;
    for (int i = t; i < 4096; i += 256) sh.r.u[i] = f2sort(aload(&col[i]));
    if (t < 2) sh.r.cnts[t] = 0;
    __syncthreads();
    radix_select_4096(sh.r.u, LQ, sh.r.hist, sh.r.wsum, sh.r.res, 0);
    const unsigned Tu = sh.r.res[0];
    const int krem = (int)sh.r.res[1];
    int* selb = sel + b * QPAD;
    for (int i = t; i < 4096; i += 256) {
        unsigned ui = sh.r.u[i];
        if (ui > Tu) {
            int p = atomicAdd(&sh.r.cnts[0], 1);
            selb[p] = i;
        } else if (ui == Tu) {
            int p = atomicAdd(&sh.r.cnts[1], 1);
            if (p < 256) sh.r.eq[p] = i;
        }
    }
    __syncthreads();
    if (t == 0) {
        int ng = sh.r.cnts[0];
        int ne = sh.r.cnts[1] < 256 ? sh.r.cnts[1] : 256;
        for (int i = 1; i < ne; ++i) {          // ties ~unique floats: ne~1
            int v = sh.r.eq[i], j = i - 1;
            while (j >= 0 && sh.r.eq[j] > v) { sh.r.eq[j+1] = sh.r.eq[j]; --j; }
            sh.r.eq[j+1] = v;
        }
        for (int j = 0; j < krem; ++j) selb[ng + j] = sh.r.eq[j];
    }
    __syncthreads();
    if (t < QPAD - LQ) selb[LQ + t] = selb[LQ - 1];   // pad (parallel)
}

// ---------------- K4: MFMA flash attention + fence-free combine ----------
// R9 attn body (54.5us). Tail: __syncthreads (drains ALL waves' pout/pl
// atomics — no threadfence), t0 signals cntA[b,qt]; the KS-th finisher
// reads pout/pl via aload (coherence point) and writes the final rows
// (mean-filled rows were written by sqk; kernel boundary ordered them).
__global__ __launch_bounds__(256, 3) void attn_kernel(
    const ushort_t* __restrict__ Qh, const ushort_t* __restrict__ Kh,
    const ushort_t* __restrict__ Vt, const int* __restrict__ sel,
    float* __restrict__ pl, float* __restrict__ pout,
    int* __restrict__ cntA, float* __restrict__ out) {
    const int qt = blockIdx.x, ks = blockIdx.y, b = blockIdx.z;
    const int t = threadIdx.x, w = t >> 6, lane = t & 63;
    const int col = lane & 31, h = lane >> 5;

    __shared__ ushort_t Ktile[2][32 * 64];
    __shared__ ushort_t Vtile[2][32 * 64];
    __shared__ int amlast;

    // persistent Q fragments (B-operand: lane holds q=col, d=16m+8h+j)
    half8 qf[4];
    {
        const int q = qt * QPB + w * 32 + col;
        const int row = sel[b * QPAD + q];
        const uint4* qg = (const uint4*)(Qh + ((size_t)b * SEQ + row) * DIM);
#pragma unroll
        for (int m = 0; m < 4; ++m) { UH u; u.u4 = qg[2 * m + h]; qf[m] = u.h; }
    }

    // loop-invariant swizzled LDS offsets (ushort elements)
    int koff[4], voff[4];
#pragma unroll
    for (int m = 0; m < 4; ++m)
        koff[m] = col * 64 + 8 * ((2 * m + h) ^ (col & 7));
#pragma unroll
    for (int i = 0; i < 4; ++i)
        voff[i] = col * 64 + 8 * ((i * 2 + h) ^ (col & 7));  // i = D*2+c

    fx16 O0, O1, Zf;
#pragma unroll
    for (int r = 0; r < 16; ++r) { O0[r] = 0.f; O1[r] = 0.f; Zf[r] = 0.f; }
    float l = 0.f;

    const int srow = t >> 3, sgr = t & 7;
    const int lg = sgr ^ (srow & 7);
    const int vD = lg >> 2, vc = (lg >> 1) & 1, vh = lg & 1;
    const size_t kgbase = ((size_t)b * SEQ + ks * 1024 + srow) * DIM + 8 * lg;
    const size_t vgbase = ((size_t)(b * DIM + srow + 32 * vD)) * SEQ
                          + ks * 1024 + vc * 16 + vh * 8;

    const int sw = srow * 64 + sgr * 8;      // staging LDS offset

    auto step = [&](int buf) {
        // S^T = K * Q^T  (f16 MFMA); Qh pre-scaled by 0.125*log2e
        UH kf0; kf0.u4 = *(const uint4*)&Ktile[buf][koff[0]];
        fx16 S = __builtin_amdgcn_mfma_f32_32x32x16_f16(kf0.h, qf[0], Zf, 0, 0, 0);
#pragma unroll
        for (int m = 1; m < 4; ++m) {
            UH kf;
            kf.u4 = *(const uint4*)&Ktile[buf][koff[m]];
            S = __builtin_amdgcn_mfma_f32_32x32x16_f16(kf.h, qf[m], S, 0, 0, 0);
        }
        // softmax numerators (no max subtraction: scores bounded « 128)
        float p[16];
#pragma unroll
        for (int r = 0; r < 16; ++r) p[r] = exp2f(S[r]);
        {
            float l01 = (p[0] + p[1]) + (p[2] + p[3]);
            float l23 = (p[4] + p[5]) + (p[6] + p[7]);
            float l45 = (p[8] + p[9]) + (p[10] + p[11]);
            float l67 = (p[12] + p[13]) + (p[14] + p[15]);
            l += (l01 + l23) + (l45 + l67);
        }
        UB A0, A1;
#pragma unroll
        for (int v = 0; v < 4; ++v) {
            A0.u[v] = pack_bf16(p[2 * v],     p[2 * v + 1]);
            A1.u[v] = pack_bf16(p[8 + 2 * v], p[8 + 2 * v + 1]);
        }
        // O += P * V  (bf16 MFMA)
#pragma unroll
        for (int D = 0; D < 2; ++D) {
            fx16& O = D ? O1 : O0;
#pragma unroll
            for (int c = 0; c < 2; ++c) {
                UB vf;
                vf.u4 = *(const uint4*)&Vtile[buf][voff[D * 2 + c]];
                O = __builtin_amdgcn_mfma_f32_32x32x16_bf16(c ? A1.s : A0.s, vf.s,
                                                            O, 0, 0, 0);
            }
        }
    };

    uint4 kA = *(const uint4*)(Kh + kgbase);
    uint4 vA = *(const uint4*)(Vt + vgbase);
    uint4 kB = *(const uint4*)(Kh + kgbase + 32 * DIM);
    uint4 vB = *(const uint4*)(Vt + vgbase + 32);

    for (int tile = 0; tile < 32; tile += 2) {
        // even tile -> buf 0 (regs A hold tile data, loaded 2 tiles ago)
        *(uint4*)&Ktile[0][sw] = kA;
        *(uint4*)&Vtile[0][sw] = vA;
        __syncthreads();
        if (tile + 2 < 32) {
            kA = *(const uint4*)(Kh + kgbase + (size_t)(tile + 2) * 32 * DIM);
            vA = *(const uint4*)(Vt + vgbase + (size_t)(tile + 2) * 32);
        }
        step(0);
        // odd tile -> buf 1
        *(uint4*)&Ktile[1][sw] = kB;
        *(uint4*)&Vtile[1][sw] = vB;
        __syncthreads();
        if (tile + 3 < 32) {
            kB = *(const uint4*)(Kh + kgbase + (size_t)(tile + 3) * 32 * DIM);
            vB = *(const uint4*)(Vt + vgbase + (size_t)(tile + 3) * 32);
        }
        step(1);
    }

    l += __shfl_xor(l, 32);   // combine the two k-halves of the column sum

    const int qg0 = qt * QPB + w * 32;
    const size_t base = (size_t)b * QPAD + qg0;
#pragma unroll
    for (int D = 0; D < 2; ++D) {
        const fx16& O = D ? O1 : O0;
#pragma unroll
        for (int r = 0; r < 16; ++r) {
            const int q = (r & 3) + 8 * (r >> 2) + 4 * h;
            atomicAdd(&pout[(base + q) * DIM + D * 32 + col], O[r]);
        }
    }
    if (h == 0) atomicAdd(&pl[base + col], l);

    // -------- fence-free last-finisher combine for this (b,qt) --------
    __syncthreads();      // compiler drains vmcnt(0) before s_barrier:
                          // ALL waves' atomics are at the coherence point
    if (t == 0) amlast = (atomicAdd(&cntA[b * NQB + qt], 1) == KS - 1);
    __syncthreads();
    if (!amlast) return;

    const size_t qb0 = (size_t)b * QPAD + qt * QPB;
    for (int idx = t; idx < QPB * 16; idx += 256) {
        const int q = idx >> 4, c = idx & 15;
        const size_t s0 = qb0 + q;
        const float invl = 1.0f / aload(&pl[s0]);
        const float* po = pout + s0 * DIM + c * 4;
        const float a0 = aload(&po[0]), a1 = aload(&po[1]);
        const float a2 = aload(&po[2]), a3 = aload(&po[3]);
        const int row = sel[b * QPAD + qt * QPB + q];
        ((float4*)(out + ((size_t)b * SEQ + row) * DIM))[c] =
            make_float4(a0 * invl, a1 * invl, a2 * invl, a3 * invl);
        // pad slots (q beyond LQ) rewrite selb[LQ-1]'s row with values
        // equal up to atomic-order rounding (~1e-7) — benign.
    }
}

// ---------------- launcher: 4 regular launches ---------------------------
extern "C" void kernel_launch(void* const* d_in, const int* in_sizes, int n_in,
                              void* d_out, int out_size, void* d_ws, size_t ws_size,
                              hipStream_t stream) {
    const float* x  = (const float*)d_in[0];
    const float* Wq = (const float*)d_in[1];
    const float* Wk = (const float*)d_in[2];
    const float* Wv = (const float*)d_in[3];
    float* out = (float*)d_out;
    char* wsb  = (char*)d_ws;

    // workspace layout (bytes), footprint 29,847,552 (Kt end) — unchanged
    float*    Q       = (float*)(wsb);                 //  8,388,608
    _Float16* Qh      = (_Float16*)(wsb + 8388608);    //  4,194,304
    _Float16* Kh      = (_Float16*)(wsb + 12582912);   //  4,194,304
    ushort_t* Vt      = (ushort_t*)(wsb + 16777216);   //  4,194,304
    float*    pmean   = (float*)(wsb + 20971520);      //  131,072
    float*    meanfin = (float*)(wsb + 21102592);      //  2,048
    float*    Kred    = (float*)(wsb + 21104640);      //  2,048
    float*    sqk     = (float*)(wsb + 21106688);      //  131,072
    int*      sel     = (int*)(wsb + 21237760);        //  90,112
    // alias region: Kt (8,388,608) -> after kmean zeroes it: pout+pl+cnts
    float*    Kt      = (float*)(wsb + 21458944);
    float*    pout    = (float*)(wsb + 21458944);      //  5,767,168
    float*    pl      = (float*)(wsb + 21458944 + 5767168);  // 90,112
    // counters INSIDE Kt (zeroed by kmean AFTER proj's Kt writes — R7 fix)
    int*      cntS    = (int*)(wsb + 27316224);        // 8 ints (sqk)
    int*      cntA    = (int*)(wsb + 27316352);        // 176 ints (attn)

    proj_kernel  <<<dim3(64, 8),          256, 0, stream>>>(x, Wq, Wk, Wv, Q, Kt,
                                                            Qh, Kh, Vt, pmean);
    // kmean zeroes the whole Kt region in place (pout, pl, cntS, cntA)
    kmean_kernel <<<512,                  256, 0, stream>>>(Kt, pmean, Kred, meanfin);
    // sqk + mean-fill + last-finisher select (counter protocol, no fences)
    sqk_select_kernel<<<dim3(16, 8),      256, 0, stream>>>(Q, Kred, sqk, meanfin,
                                                            cntS, sel, out);
    // attn + fence-free last-finisher combine
    attn_kernel  <<<dim3(NQB, KS, BATCH), 256, 0, stream>>>((const ushort_t*)Qh,
                                                            (const ushort_t*)Kh,
                                                            Vt, sel, pl, pout,
                                                            cntA, out);
}

// Round 13
// 183.118 us; speedup vs baseline: 1.8358x; 1.8358x over previous
//
#include <hip/hip_runtime.h>
#include <hip/hip_bf16.h>
#include <math.h>

#define BATCH 8
#define SEQ   4096
#define DIM   64
#define LQ    2744            // int((1-0.33)*4096)
#define QPB   128             // queries per attn block
#define NQB   22              // ceil(2744/128)
#define QPAD  2816            // NQB*QPB
#define KS    4               // key splits (1024 keys per block) — R0 config
#define QSC   0.1803368801111204f   // 0.125 * log2(e), folded into Qh

typedef _Float16 half8 __attribute__((ext_vector_type(8)));
typedef short    bs8   __attribute__((ext_vector_type(8)));
typedef float    fx16  __attribute__((ext_vector_type(16)));
typedef unsigned short ushort_t;

union UH { uint4 u4; half8 h; };
union UB { unsigned u[4]; uint4 u4; bs8 s; };

__device__ __forceinline__ unsigned pack_bf16(float a, float b) {
    __hip_bfloat162 h = __float22bfloat162_rn(make_float2(a, b));
    union { __hip_bfloat162 h; unsigned u; } cv; cv.h = h; return cv.u;
}

// ---------------- sortable-uint mapping ----------------
__device__ __forceinline__ unsigned f2sort(float f) {
    unsigned u = __float_as_uint(f);
    return (u & 0x80000000u) ? ~u : (u | 0x80000000u);
}
__device__ __forceinline__ float sort2f(unsigned u) {
    return __uint_as_float((u & 0x80000000u) ? (u & 0x7FFFFFFFu) : ~u);
}

struct RadSh {
    unsigned u[4096];
    unsigned hist[256];
    unsigned wsum[4];
    unsigned res[2];
    float    rsum[4];
    int      eq[256];
    int      cnts[2];
};

// ---------------- radix select, wave-level suffix scan (256 threads) -----
// pass_lo=0 exact 32-bit threshold; pass_lo=2 -> 16-bit prefix threshold
// (caller approximates the remainder bin).
__device__ void radix_select_4096(const unsigned* u, int k, unsigned* hist,
                                  unsigned* wsum, unsigned* res, int pass_lo) {
    const int t = threadIdx.x;
    const int lane = t & 63, wv = t >> 6;
    if (t == 0) { res[0] = 0u; res[1] = (unsigned)k; }
    for (int pass = 3; pass >= pass_lo; --pass) {
        const int shift = pass * 8;
        hist[t] = 0u;
        __syncthreads();
        const unsigned pref  = res[0];
        const unsigned kk    = res[1];
        const unsigned hmask = (pass == 3) ? 0u : (0xFFFFFFFFu << (shift + 8));
        for (int i = t; i < 4096; i += 256) {
            unsigned ui = u[i];
            if ((ui & hmask) == pref) atomicAdd(&hist[(ui >> shift) & 255u], 1u);
        }
        __syncthreads();
        const unsigned h = hist[t];
        unsigned s = h;
#pragma unroll
        for (int ofs = 1; ofs < 64; ofs <<= 1) {
            unsigned a = __shfl_down(s, ofs, 64);
            s += (lane + ofs < 64) ? a : 0u;
        }
        if (lane == 0) wsum[wv] = s;     // wave total (suffix at lane 0)
        __syncthreads();
#pragma unroll
        for (int w2 = 0; w2 < 4; ++w2)
            if (w2 > wv) s += wsum[w2];  // s = sum of hist[t..255]
        if (s >= kk && (s - h) < kk) {   // unique threshold bin
            res[0] = pref | ((unsigned)t << shift);
            res[1] = kk - (s - h);
        }
        __syncthreads();
    }
}

// ---------------- K1: projections (R3, proven) ---------------------------
// x rows are wave-uniform: readfirstlane-forced scalar loads.
__global__ __launch_bounds__(256) void proj_kernel(
    const float* __restrict__ x,  const float* __restrict__ Wq,
    const float* __restrict__ Wk, const float* __restrict__ Wv,
    float* __restrict__ Q, float* __restrict__ Kt,
    _Float16* __restrict__ Qh, _Float16* __restrict__ Kh,
    ushort_t* __restrict__ Vt, float* __restrict__ pmean) {
    const int rt = blockIdx.x, b = blockIdx.y, t = threadIdx.x;
    __shared__ float  red[4][64];
    const int ch = t & 63, rg = t >> 6;
    const float* xb = x + (size_t)b * SEQ * DIM;
    float accq[16], acck[16], accv[16];
#pragma unroll
    for (int i = 0; i < 16; ++i) { accq[i] = 0.f; acck[i] = 0.f; accv[i] = 0.f; }
    for (int dc = 0; dc < 4; ++dc) {
        float wq[16], wk[16], wv[16];
#pragma unroll
        for (int dd = 0; dd < 16; ++dd) {
            int d = dc * 16 + dd;
            wq[dd] = Wq[d * 64 + ch]; wk[dd] = Wk[d * 64 + ch]; wv[dd] = Wv[d * 64 + ch];
        }
        for (int r = 0; r < 16; ++r) {
            const int off = (rt * 64 + rg * 16 + r) * DIM + dc * 16;
            const float* xrow =
                xb + (unsigned)__builtin_amdgcn_readfirstlane(off);
            float xv[16];
#pragma unroll
            for (int dd = 0; dd < 16; ++dd) xv[dd] = xrow[dd];
#pragma unroll
            for (int dd = 0; dd < 16; ++dd) {
                accq[r] = fmaf(xv[dd], wq[dd], accq[r]);
                acck[r] = fmaf(xv[dd], wk[dd], acck[r]);
                accv[r] = fmaf(xv[dd], wv[dd], accv[r]);
            }
        }
    }
    const int rowbase = rt * 64 + rg * 16;
    float sv = 0.f;
#pragma unroll
    for (int r = 0; r < 16; ++r) {
        size_t o = ((size_t)b * SEQ + rowbase + r) * DIM + ch;
        Q[o]  = accq[r];
        Qh[o] = (_Float16)(accq[r] * QSC);
        Kh[o] = (_Float16)acck[r];
        sv += accv[r];
    }
    float4* ktp = (float4*)(Kt + ((size_t)b * 64 + ch) * SEQ + rowbase);
    ktp[0] = make_float4(acck[0], acck[1], acck[2], acck[3]);
    ktp[1] = make_float4(acck[4], acck[5], acck[6], acck[7]);
    ktp[2] = make_float4(acck[8], acck[9], acck[10], acck[11]);
    ktp[3] = make_float4(acck[12], acck[13], acck[14], acck[15]);
    // Vt bf16, k-permuted pair order per 16-group: [0,1,4,5,2,3,6,7]
    {
        unsigned pk[8];
#pragma unroll
        for (int i = 0; i < 8; ++i) pk[i] = pack_bf16(accv[2*i], accv[2*i+1]);
        uint4* vp = (uint4*)(Vt + ((size_t)(b * 64 + ch)) * SEQ + rowbase);
        vp[0] = make_uint4(pk[0], pk[1], pk[4], pk[5]);
        vp[1] = make_uint4(pk[2], pk[3], pk[6], pk[7]);
    }
    red[rg][ch] = sv;
    __syncthreads();
    if (rg == 0)
        pmean[((size_t)b * 64 + ch) * 64 + rt] =
            red[0][ch] + red[1][ch] + red[2][ch] + red[3][ch];
}

// ---------------- K2: kmean (R3, proven: 2-pass radix) -------------------
__global__ __launch_bounds__(256) void kmean_kernel(const float* __restrict__ Kt,
                                                    const float* __restrict__ pmean,
                                                    float* __restrict__ Kred,
                                                    float* __restrict__ meanfin) {
    __shared__ RadSh sh;
    const int bc = blockIdx.x, t = threadIdx.x;
    if (t < 64) {
        float v = pmean[(size_t)bc * 64 + t];
        for (int m = 1; m < 64; m <<= 1) v += __shfl_xor(v, m, 64);
        if (t == 0) meanfin[bc] = v * (1.0f / (float)SEQ);
    }
    const float4* c4 = (const float4*)(Kt + (size_t)bc * SEQ);
    for (int i = t; i < 1024; i += 256) {
        float4 v = c4[i];
        sh.u[i*4+0] = f2sort(v.x); sh.u[i*4+1] = f2sort(v.y);
        sh.u[i*4+2] = f2sort(v.z); sh.u[i*4+3] = f2sort(v.w);
    }
    __syncthreads();
    radix_select_4096(sh.u, LQ, sh.hist, sh.wsum, sh.res, 2);
    const unsigned Tu = sh.res[0];          // bits 31..16 of threshold
    const int krem = (int)sh.res[1];
    float loc = 0.f;
    for (int i = t; i < 4096; i += 256)
        if ((sh.u[i] & 0xFFFF0000u) > Tu) loc += sort2f(sh.u[i]);
    for (int msk = 1; msk < 64; msk <<= 1) loc += __shfl_xor(loc, msk, 64);
    if ((t & 63) == 0) sh.rsum[t >> 6] = loc;
    __syncthreads();
    if (t == 0) {
        float s = sh.rsum[0] + sh.rsum[1] + sh.rsum[2] + sh.rsum[3]
                + (float)krem * sort2f(Tu | 0x8000u);   // bin midpoint
        Kred[bc] = s / (float)LQ;
    }
}

// ---------------- K3: sqk = K_reduce . Q; also zero attn partials --------
// R3-proven: 128 blocks carry the 5.86MB zeroing + 8.4MB Q reads (R8/R10
// lesson: never narrow bandwidth-carrying work to save a launch).
__global__ __launch_bounds__(256) void sqk_kernel(const float* __restrict__ Q,
                                                  const float* __restrict__ Kred,
                                                  float* __restrict__ sqk,
                                                  float4* __restrict__ pz) {
    const int b = blockIdx.y, l = blockIdx.x * 256 + threadIdx.x;
    __shared__ float kr[64];
    if (threadIdx.x < 64) kr[threadIdx.x] = Kred[b * 64 + threadIdx.x];
    // zero pout+pl (5,857,280 B = 366,080 float4) — replaces hipMemsetAsync
    {
        const int tid = (blockIdx.y * 16 + blockIdx.x) * 256 + threadIdx.x;
        const float4 z = make_float4(0.f, 0.f, 0.f, 0.f);
        for (int i = tid; i < 366080; i += 32768) pz[i] = z;
    }
    __syncthreads();
    const float4* q = (const float4*)(Q + ((size_t)b * SEQ + l) * DIM);
    float s = 0.f;
#pragma unroll
    for (int i = 0; i < 16; ++i) {
        float4 v = q[i];
        s = fmaf(v.x, kr[i*4+0], s); s = fmaf(v.y, kr[i*4+1], s);
        s = fmaf(v.z, kr[i*4+2], s); s = fmaf(v.w, kr[i*4+3], s);
    }
    sqk[b * SEQ + l] = s;
}

// ---------------- K4: per-batch top-LQ selection + inverse map -----------
__global__ __launch_bounds__(256) void select_kernel(const float* __restrict__ sqk,
                                                     int* __restrict__ sel,
                                                     int* __restrict__ inv) {
    __shared__ RadSh r;
    const int b = blockIdx.x, t = threadIdx.x;
    const float* col = sqk + (size_t)b * SEQ;
    int* invb = inv + (size_t)b * SEQ;
    for (int i = t; i < 4096; i += 256) {
        r.u[i] = f2sort(col[i]);
        invb[i] = -1;
    }
    if (t < 2) r.cnts[t] = 0;
    __syncthreads();
    radix_select_4096(r.u, LQ, r.hist, r.wsum, r.res, 0);
    const unsigned Tu = r.res[0];
    const int krem = (int)r.res[1];
    int* selb = sel + b * QPAD;
    for (int i = t; i < 4096; i += 256) {
        unsigned ui = r.u[i];
        if (ui > Tu) {
            int p = atomicAdd(&r.cnts[0], 1);
            selb[p] = i;
            invb[i] = p;
        } else if (ui == Tu) {
            int p = atomicAdd(&r.cnts[1], 1);
            if (p < 256) r.eq[p] = i;
        }
    }
    __syncthreads();
    if (t == 0) {
        int ng = r.cnts[0];
        int ne = r.cnts[1] < 256 ? r.cnts[1] : 256;
        for (int i = 1; i < ne; ++i) {          // ties ~unique floats: ne~1
            int v = r.eq[i], j = i - 1;
            while (j >= 0 && r.eq[j] > v) { r.eq[j+1] = r.eq[j]; --j; }
            r.eq[j+1] = v;
        }
        for (int j = 0; j < krem; ++j) {
            selb[ng + j] = r.eq[j];
            invb[r.eq[j]] = ng + j;
        }
    }
    __syncthreads();
    if (t < QPAD - LQ) selb[LQ + t] = selb[LQ - 1];   // pad (parallel)
}

// ---------------- K5: MFMA flash attention (R0 + 2-deep prefetch) --------
// Best measured attn (54.5us). Cross-block sync is kernel-boundary ONLY:
// fences storm L2 writebacks (R11), atomic-RMW reads re-dirty pout (R12),
// cooperative launch no-ops under graph capture (R5/R6). Structure:
// KS=4 splits, KTILE=32, one barrier/tile, depth-2 register prefetch.
__global__ __launch_bounds__(256, 3) void attn_kernel(
    const ushort_t* __restrict__ Qh, const ushort_t* __restrict__ Kh,
    const ushort_t* __restrict__ Vt, const int* __restrict__ sel,
    float* __restrict__ pl, float* __restrict__ pout) {
    const int qt = blockIdx.x, ks = blockIdx.y, b = blockIdx.z;
    const int t = threadIdx.x, w = t >> 6, lane = t & 63;
    const int col = lane & 31, h = lane >> 5;

    __shared__ ushort_t Ktile[2][32 * 64];
    __shared__ ushort_t Vtile[2][32 * 64];

    // persistent Q fragments (B-operand: lane holds q=col, d=16m+8h+j)
    half8 qf[4];
    {
        const int q = qt * QPB + w * 32 + col;
        const int row = sel[b * QPAD + q];
        const uint4* qg = (const uint4*)(Qh + ((size_t)b * SEQ + row) * DIM);
#pragma unroll
        for (int m = 0; m < 4; ++m) { UH u; u.u4 = qg[2 * m + h]; qf[m] = u.h; }
    }

    // loop-invariant swizzled LDS offsets (ushort elements)
    int koff[4], voff[4];
#pragma unroll
    for (int m = 0; m < 4; ++m)
        koff[m] = col * 64 + 8 * ((2 * m + h) ^ (col & 7));
#pragma unroll
    for (int i = 0; i < 4; ++i)
        voff[i] = col * 64 + 8 * ((i * 2 + h) ^ (col & 7));  // i = D*2+c

    fx16 O0, O1;
#pragma unroll
    for (int r = 0; r < 16; ++r) { O0[r] = 0.f; O1[r] = 0.f; }
    float l = 0.f;

    const int srow = t >> 3, sgr = t & 7;
    const int lg = sgr ^ (srow & 7);
    const int vD = lg >> 2, vc = (lg >> 1) & 1, vh = lg & 1;
    const size_t kgbase = ((size_t)b * SEQ + ks * 1024 + srow) * DIM + 8 * lg;
    const size_t vgbase = ((size_t)(b * DIM + srow + 32 * vD)) * SEQ
                          + ks * 1024 + vc * 16 + vh * 8;

    const int sw = srow * 64 + sgr * 8;      // staging LDS offset

    auto step = [&](int buf) {
        // S^T = K * Q^T  (f16 MFMA); Qh pre-scaled by 0.125*log2e
        fx16 S;
#pragma unroll
        for (int r = 0; r < 16; ++r) S[r] = 0.f;
#pragma unroll
        for (int m = 0; m < 4; ++m) {
            UH kf;
            kf.u4 = *(const uint4*)&Ktile[buf][koff[m]];
            S = __builtin_amdgcn_mfma_f32_32x32x16_f16(kf.h, qf[m], S, 0, 0, 0);
        }
        // softmax numerators (no max subtraction: scores bounded « 128)
        float p[16];
#pragma unroll
        for (int r = 0; r < 16; ++r) p[r] = exp2f(S[r]);
#pragma unroll
        for (int r = 0; r < 16; ++r) l += p[r];
        UB A0, A1;
#pragma unroll
        for (int v = 0; v < 4; ++v) {
            A0.u[v] = pack_bf16(p[2 * v],     p[2 * v + 1]);
            A1.u[v] = pack_bf16(p[8 + 2 * v], p[8 + 2 * v + 1]);
        }
        // O += P * V  (bf16 MFMA)
#pragma unroll
        for (int D = 0; D < 2; ++D) {
            fx16& O = D ? O1 : O0;
#pragma unroll
            for (int c = 0; c < 2; ++c) {
                UB vf;
                vf.u4 = *(const uint4*)&Vtile[buf][voff[D * 2 + c]];
                O = __builtin_amdgcn_mfma_f32_32x32x16_bf16(c ? A1.s : A0.s, vf.s,
                                                            O, 0, 0, 0);
            }
        }
    };

    uint4 kA = *(const uint4*)(Kh + kgbase);
    uint4 vA = *(const uint4*)(Vt + vgbase);
    uint4 kB = *(const uint4*)(Kh + kgbase + 32 * DIM);
    uint4 vB = *(const uint4*)(Vt + vgbase + 32);

    for (int tile = 0; tile < 32; tile += 2) {
        // even tile -> buf 0 (regs A hold tile data, loaded 2 tiles ago)
        *(uint4*)&Ktile[0][sw] = kA;
        *(uint4*)&Vtile[0][sw] = vA;
        __syncthreads();
        if (tile + 2 < 32) {
            kA = *(const uint4*)(Kh + kgbase + (size_t)(tile + 2) * 32 * DIM);
            vA = *(const uint4*)(Vt + vgbase + (size_t)(tile + 2) * 32);
        }
        step(0);
        // odd tile -> buf 1
        *(uint4*)&Ktile[1][sw] = kB;
        *(uint4*)&Vtile[1][sw] = vB;
        __syncthreads();
        if (tile + 3 < 32) {
            kB = *(const uint4*)(Kh + kgbase + (size_t)(tile + 3) * 32 * DIM);
            vB = *(const uint4*)(Vt + vgbase + (size_t)(tile + 3) * 32);
        }
        step(1);
    }

    l += __shfl_xor(l, 32);   // combine the two k-halves of the column sum

    const int qg0 = qt * QPB + w * 32;
    const size_t base = (size_t)b * QPAD + qg0;
#pragma unroll
    for (int D = 0; D < 2; ++D) {
        const fx16& O = D ? O1 : O0;
#pragma unroll
        for (int r = 0; r < 16; ++r) {
            const int q = (r & 3) + 8 * (r >> 2) + 4 * h;
            atomicAdd(&pout[(base + q) * DIM + D * 32 + col], O[r]);
        }
    }
    if (h == 0) atomicAdd(&pl[base + col], l);
}

// ---------------- K6: normalize+scatter OR mean-fill (R0 verbatim) -------
__global__ __launch_bounds__(256) void comb_kernel(
    const float* __restrict__ pl, const float* __restrict__ pout,
    const int* __restrict__ inv, const float* __restrict__ meanfin,
    float* __restrict__ out) {
    const int idx = blockIdx.x * 256 + threadIdx.x;   // over BATCH*SEQ*16
    const int b = idx >> 16;
    const int rc = idx & 65535;
    const int row = rc >> 4, c = rc & 15;
    const int p = inv[b * SEQ + row];
    float4 o;
    if (p >= 0) {
        const size_t s0 = (size_t)b * QPAD + p;
        const float invl = 1.0f / pl[s0];
        float4 a = ((const float4*)(pout + s0 * DIM))[c];
        o = make_float4(a.x * invl, a.y * invl, a.z * invl, a.w * invl);
    } else {
        o = make_float4(meanfin[b * 64 + c * 4 + 0], meanfin[b * 64 + c * 4 + 1],
                        meanfin[b * 64 + c * 4 + 2], meanfin[b * 64 + c * 4 + 3]);
    }
    ((float4*)out)[idx] = o;
}

// ---------------- launcher: 6 regular launches ---------------------------
extern "C" void kernel_launch(void* const* d_in, const int* in_sizes, int n_in,
                              void* d_out, int out_size, void* d_ws, size_t ws_size,
                              hipStream_t stream) {
    const float* x  = (const float*)d_in[0];
    const float* Wq = (const float*)d_in[1];
    const float* Wk = (const float*)d_in[2];
    const float* Wv = (const float*)d_in[3];
    float* out = (float*)d_out;
    char* wsb  = (char*)d_ws;

    // workspace layout (bytes), total ~29.9 MB
    float*    Q       = (float*)(wsb);                 //  8,388,608
    _Float16* Qh      = (_Float16*)(wsb + 8388608);    //  4,194,304
    _Float16* Kh      = (_Float16*)(wsb + 12582912);   //  4,194,304
    ushort_t* Vt      = (ushort_t*)(wsb + 16777216);   //  4,194,304
    float*    pmean   = (float*)(wsb + 20971520);      //  131,072
    float*    meanfin = (float*)(wsb + 21102592);      //  2,048
    float*    Kred    = (float*)(wsb + 21104640);      //  2,048
    float*    sqk     = (float*)(wsb + 21106688);      //  131,072
    int*      sel     = (int*)(wsb + 21237760);        //  90,112
    int*      inv     = (int*)(wsb + 21327872);        //  131,072
    // alias region: Kt (8,388,608) until kmean consumes it; then pout+pl
    float*    Kt      = (float*)(wsb + 21458944);
    float*    pout    = (float*)(wsb + 21458944);      //  5,767,168
    float*    pl      = (float*)(wsb + 21458944 + 5767168);  // 90,112

    proj_kernel  <<<dim3(64, 8),          256, 0, stream>>>(x, Wq, Wk, Wv, Q, Kt,
                                                            Qh, Kh, Vt, pmean);
    kmean_kernel <<<512,                  256, 0, stream>>>(Kt, pmean, Kred, meanfin);
    // sqk also zeroes pout+pl (Kt dead after kmean; alias region reused)
    sqk_kernel   <<<dim3(16, 8),          256, 0, stream>>>(Q, Kred, sqk,
                                                            (float4*)pout);
    select_kernel<<<8,                    256, 0, stream>>>(sqk, sel, inv);
    attn_kernel  <<<dim3(NQB, KS, BATCH), 256, 0, stream>>>((const ushort_t*)Qh,
                                                            (const ushort_t*)Kh,
                                                            Vt, sel, pl, pout);
    comb_kernel  <<<2048,                 256, 0, stream>>>(pl, pout, inv, meanfin, out);
}